// Round 11
// baseline (117.429 us; speedup 1.0000x reference)
//
#include <hip/hip_runtime.h>
#include <hip/hip_bf16.h>
#include <stdint.h>

// DIAGNOSTIC ROUND: real r10 pipeline + two amplified twins (to d_ws) to get
// per-phase rocprof counters. Real output path is byte-identical to r10.
//
// out[n,f,i,j] = sum_k W[f,k]*patch[n,i,j,k] - 0.5||W_f||^2 - 0.5||X_{n,i,j}||^2

#define N_IMG 32
#define C_IN 128
#define H_IN 28
#define HP 32
#define HO 30
#define P_SP 900
#define F_OUT 128
#define K_TOT 1152

#define BLT 60
#define TPI 15
#define NBLK (N_IMG*TPI)    // 480
#define NSTEP 18

typedef __attribute__((ext_vector_type(8))) short bf16x8;
typedef __attribute__((ext_vector_type(4))) unsigned short u16x4;
typedef __attribute__((ext_vector_type(8))) unsigned short u16x8;
typedef __attribute__((ext_vector_type(4))) float f32x4;

__device__ __forceinline__ unsigned short f2bf(float f) {
  union { float f; unsigned u; } t; t.f = f;
  unsigned r = t.u + 0x7fffu + ((t.u >> 16) & 1u);
  return (unsigned short)(r >> 16);
}

__global__ void prep_w_kernel(const float* __restrict__ W,
                              unsigned short* __restrict__ Wbf,
                              float* __restrict__ wnorm) {
  int f = blockIdx.x;
  const float* Wf = W + f * K_TOT;
  float part = 0.f;
  for (int k = threadIdx.x; k < K_TOT; k += 256) {
    float v = Wf[k];
    part += v * v;
    int ch = k / 9, rr = k - ch * 9;
    Wbf[f * K_TOT + rr * 128 + ch] = f2bf(v);
  }
  __shared__ float red[256];
  red[threadIdx.x] = part;
  __syncthreads();
  for (int st = 128; st > 0; st >>= 1) {
    if (threadIdx.x < st) red[threadIdx.x] += red[threadIdx.x + st];
    __syncthreads();
  }
  if (threadIdx.x == 0) wnorm[f] = 0.5f * red[0];
}

// LREP: K-loop repeats (acc accumulates across reps -> no DCE).
// PREP_REP: prologue repeats (LDS stores+barriers, not DCE-able).
template<int LREP, int PREP_REP>
__global__ __launch_bounds__(256, 2) void adder_fused_kernel(
    const float* __restrict__ x,
    const unsigned short* __restrict__ Wbf,
    const float* __restrict__ wnorm,
    float* __restrict__ out) {
  __shared__ unsigned short xfoot[128 * 130];
  __shared__ unsigned short A_lds[2][64 * 128];
  __shared__ float pixsum_s[128];
  __shared__ float xn_s[64];
  __shared__ float wn_s[F_OUT];

  int tid = threadIdx.x, lane = tid & 63, wid = tid >> 6;
  int bid0 = blockIdx.x;
  int bid = (bid0 & 7) * (NBLK / 8) + (bid0 >> 3);
  int n = bid / TPI, timg = bid - n * TPI;
  int i0 = timg * 2, p0 = timg * BLT;

  char* XF = (char*)xfoot;
  char* A0 = (char*)&A_lds[0][0];
  char* A1 = (char*)&A_lds[1][0];
  const char* WbfB = (const char*)Wbf;

  int kb = ((lane & 7) * 16) ^ ((lane >> 3) << 4);
  int a_goff[4];
#pragma unroll
  for (int a = 0; a < 4; a++) {
    int q = a * 4 + wid;
    int rowf = q * 8 + (lane >> 3);
    a_goff[a] = rowf * (K_TOT * 2) + kb;
  }
  int a_loff = wid * 1024 + lane * 16;

  auto STAGE = [&](int t, char* AB) {
    int off = t * 128;
#pragma unroll
    for (int a = 0; a < 4; a++)
      __builtin_amdgcn_global_load_lds(
          (const __attribute__((address_space(1))) void*)(WbfB + a_goff[a] + off),
          (__attribute__((address_space(3))) void*)(AB + a * 4096 + a_loff), 16, 0, 0);
  };

  if (tid < F_OUT) wn_s[tid] = wnorm[tid];
  STAGE(0, A0);
  STAGE(1, A1);

  for (int pr = 0; pr < PREP_REP; pr++) {
    // x conversion, coalesced mapping: u = cq*28 + r*7 + w4.
    for (int u = tid; u < 896; u += 256) {
      int cq = u / 28, rem = u - cq * 28;
      int r = rem / 7, w4 = rem - r * 7;
      int c = cq * 4;
      int hr = i0 - 2 + r;
      float vv[4][4];
      if (hr >= 0 && hr < H_IN) {
#pragma unroll
        for (int q = 0; q < 4; q++) {
          float4 t4 = *(const float4*)(x + (((n * C_IN + c + q) * H_IN + hr) * H_IN + w4 * 4));
          vv[q][0] = t4.x; vv[q][1] = t4.y; vv[q][2] = t4.z; vv[q][3] = t4.w;
        }
      } else {
#pragma unroll
        for (int q = 0; q < 4; q++)
#pragma unroll
          for (int e = 0; e < 4; e++) vv[q][e] = 0.f;
      }
#pragma unroll
      for (int e = 0; e < 4; e++) {
        int wp = w4 * 4 + e + 2;
        int pix = r * 32 + wp;
        u16x4 o;
#pragma unroll
        for (int q = 0; q < 4; q++) o[q] = f2bf(vv[q][e]);
        *(u16x4*)(XF + pix * 256 + ((c * 2) ^ ((pix & 15) << 4))) = o;
      }
    }
    {
      int r = tid >> 6, wi = (tid >> 4) & 3, slot = tid & 15;
      int wp = (wi < 2) ? wi : 28 + wi;
      int pix = r * 32 + wp;
      u16x8 z;
#pragma unroll
      for (int q = 0; q < 8; q++) z[q] = 0;
      *(u16x8*)(XF + pix * 256 + ((slot * 16) ^ ((pix & 15) << 4))) = z;
    }
    __syncthreads();
    {
      int pix = tid >> 1, ch = tid & 1;
      float ssum = 0.f;
#pragma unroll
      for (int q = 0; q < 8; q++) {
        u16x8 v8 = *(const u16x8*)(XF + pix * 256 + (((ch * 128) + q * 16) ^ ((pix & 15) << 4)));
#pragma unroll
        for (int e = 0; e < 8; e++) {
          union { unsigned u; float f; } cv; cv.u = ((unsigned)v8[e]) << 16;
          ssum += cv.f * cv.f;
        }
      }
      ssum += __shfl_xor(ssum, 1);
      if (!ch) pixsum_s[pix] = ssum;
    }
    __syncthreads();
    if (tid < BLT) {
      int il = tid / HO, j = tid - il * HO;
      float a9 = 0.f;
#pragma unroll
      for (int dh = 0; dh < 3; dh++)
#pragma unroll
        for (int dw = 0; dw < 3; dw++)
          a9 += pixsum_s[(il + dh) * 32 + (j + dw)];
      xn_s[tid] = 0.5f * a9;
    }
    __syncthreads();
  }

  f32x4 acc[4][2];
#pragma unroll
  for (int mi = 0; mi < 4; mi++)
#pragma unroll
    for (int ni = 0; ni < 2; ni++)
      acc[mi][ni] = (f32x4){0.f, 0.f, 0.f, 0.f};

  int wr = wid >> 1, wc = wid & 1;
  int pix0[2];
#pragma unroll
  for (int ni = 0; ni < 2; ni++) {
    int cc = wc * 32 + ni * 16 + (lane & 15);
    if (cc > BLT - 1) cc = BLT - 1;
    int il = cc / HO, j = cc - il * HO;
    pix0[ni] = il * 32 + j;
  }
  int kfrag = (lane >> 4) * 16;

  for (int rep = 0; rep < LREP; rep++) {
    if (rep > 0) {          // re-prime for amplified twins
      STAGE(0, A0);
      STAGE(1, A1);
      asm volatile("s_waitcnt vmcnt(4)" ::: "memory");
      __builtin_amdgcn_s_barrier();
    }
#pragma unroll 2
    for (int t = 0; t < NSTEP; t++) {
      char* ABc = (t & 1) ? A1 : A0;
      int rr = t >> 1, half = t & 1;
      int dh = rr / 3, dw = rr - 3 * dh;
      int pofs = dh * 32 + dw;
      int bbase = half * 128;
#pragma unroll
      for (int kc = 0; kc < 2; kc++) {
        bf16x8 af[4], bfv[2];
#pragma unroll
        for (int mi = 0; mi < 4; mi++) {
          int rowf = wr * 64 + mi * 16 + (lane & 15);
          af[mi] = *(const bf16x8*)(ABc + rowf * 128 + ((kc * 64 + kfrag) ^ ((rowf & 7) << 4)));
        }
#pragma unroll
        for (int ni = 0; ni < 2; ni++) {
          int pix = pix0[ni] + pofs;
          bfv[ni] = *(const bf16x8*)(XF + pix * 256 + ((bbase + kc * 64 + kfrag) ^ ((pix & 15) << 4)));
        }
        __builtin_amdgcn_s_setprio(1);
#pragma unroll
        for (int mi = 0; mi < 4; mi++)
#pragma unroll
          for (int ni = 0; ni < 2; ni++)
            acc[mi][ni] = __builtin_amdgcn_mfma_f32_16x16x32_bf16(
                af[mi], bfv[ni], acc[mi][ni], 0, 0, 0);
        __builtin_amdgcn_s_setprio(0);
      }
      __builtin_amdgcn_s_barrier();
      if (t + 2 < NSTEP) {
        STAGE(t + 2, ABc);
        asm volatile("s_waitcnt vmcnt(4)" ::: "memory");
        __builtin_amdgcn_s_barrier();
      } else if (t + 2 == NSTEP) {
        asm volatile("s_waitcnt vmcnt(0)" ::: "memory");
        __builtin_amdgcn_s_barrier();
      }
    }
  }
  __syncthreads();

  float* Cst = (float*)xfoot;
  int colc = lane & 15, kg = lane >> 4;
#pragma unroll
  for (int mi = 0; mi < 4; mi++) {
    int f0 = wr * 64 + mi * 16 + kg * 4;
#pragma unroll
    for (int ni = 0; ni < 2; ni++) {
      int cc = wc * 32 + ni * 16 + colc;
#pragma unroll
      for (int r = 0; r < 4; r++)
        Cst[(f0 + r) * 65 + cc] = acc[mi][ni][r];
    }
  }
  __syncthreads();
  {
    int col = tid & 63, fq = tid >> 6;
    if (col < BLT) {
      float xn = xn_s[col];
      float* ob = out + (size_t)n * (F_OUT * P_SP) + p0 + col;
#pragma unroll
      for (int q = 0; q < 32; q++) {
        int f = fq * 32 + q;
        __builtin_nontemporal_store(Cst[f * 65 + col] - wn_s[f] - xn, ob + f * P_SP);
      }
    }
  }
}

// ---------------------------------------------------------------------------
extern "C" void kernel_launch(void* const* d_in, const int* in_sizes, int n_in,
                              void* d_out, int out_size, void* d_ws, size_t ws_size,
                              hipStream_t stream) {
  const float* x = (const float*)d_in[0];
  const float* W = (const float*)d_in[1];
  float* out = (float*)d_out;

  char* ws = (char*)d_ws;
  unsigned short* Wbf = (unsigned short*)(ws);       // 294,912 B
  float* wnorm = (float*)(ws + 294912);              //     512 B
  float* twin_out = (float*)(ws + 1048576);          // 14.7 MB scratch sink

  prep_w_kernel<<<F_OUT, 256, 0, stream>>>(W, Wbf, wnorm);
  // real (r10-identical)
  adder_fused_kernel<1, 1><<<NBLK, 256, 0, stream>>>(x, Wbf, wnorm, out);
  // twin1: 6x K-loop -> isolates loop cost L = (dur - base)/5
  adder_fused_kernel<6, 1><<<NBLK, 256, 0, stream>>>(x, Wbf, wnorm, twin_out);
  // twin2: 6x prologue -> isolates prologue cost P = (dur - base)/5
  adder_fused_kernel<1, 6><<<NBLK, 256, 0, stream>>>(x, Wbf, wnorm, twin_out);
}

// Round 12
// 28.078 us; speedup vs baseline: 4.1823x; 4.1823x over previous
//
#include <hip/hip_runtime.h>
#include <hip/hip_bf16.h>
#include <stdint.h>

// out[n,f,i,j] = sum_k W[f,k]*patch[n,i,j,k] - 0.5||W_f||^2 - 0.5||X_{n,i,j}||^2
// x: (32,128,28,28) f32 ; W: (128,128,3,3) f32 ; out: (32,128,30,30) f32
// pad=2, ho=wo=30, L=28800, K=1152, F=128

#define N_IMG 32
#define C_IN 128
#define H_IN 28
#define HP 32
#define HO 30
#define P_SP 900
#define F_OUT 128
#define K_TOT 1152

#define BLT 60              // L-tile: 2 raster rows, no image crossing
#define TPI 15              // tiles per image
#define NBLK (N_IMG*TPI)    // 480 blocks; ~35 KB LDS
#define NSTEP 18

typedef __attribute__((ext_vector_type(8))) short bf16x8;
typedef __attribute__((ext_vector_type(4))) unsigned short u16x4;
typedef __attribute__((ext_vector_type(8))) unsigned short u16x8;
typedef __attribute__((ext_vector_type(4))) float f32x4;

__device__ __forceinline__ unsigned short f2bf(float f) {
  union { float f; unsigned u; } t; t.f = f;
  unsigned r = t.u + 0x7fffu + ((t.u >> 16) & 1u);
  return (unsigned short)(r >> 16);
}

// ---------------------------------------------------------------------------
// Kernel 1: W -> Wfrag in MFMA-FRAGMENT-MAJOR layout + wnorm = 0.5||W_f||^2.
// Layout: byte ((rr*4+ks)*8 + rblk)*1024 + (kg*16 + colc)*16 holds the 8 bf16
//   W[f = rblk*16+colc][ch = ks*32+kg*8 .. +8][rr]  (k' = rr*128 + ch).
// A wave's af[mi] load becomes 64 lanes x 16B = 1KB CONTIGUOUS.
// grid 128 (f), 256 threads (144 active for the reorder).
// ---------------------------------------------------------------------------
__global__ void prep_w_kernel(const float* __restrict__ W,
                              unsigned short* __restrict__ Wfrag,
                              float* __restrict__ wnorm) {
  int f = blockIdx.x;
  const float* Wf = W + f * K_TOT;
  int t = threadIdx.x;
  float part = 0.f;
  if (t < 144) {
    int rr = t / 16, rem = t & 15;       // rr 0..8
    int ks = rem >> 2, kg = rem & 3;
    u16x8 o;
#pragma unroll
    for (int e = 0; e < 8; e++) {
      int ch = ks * 32 + kg * 8 + e;
      float v = Wf[ch * 9 + rr];
      part += v * v;
      o[e] = f2bf(v);
    }
    // ushort-unit offset: bytes/2
    int off = ((rr * 4 + ks) * 8 + (f >> 4)) * 512 + (kg * 16 + (f & 15)) * 8;
    *(u16x8*)(&Wfrag[off]) = o;
  }
  __shared__ float red[256];
  red[t] = part;
  __syncthreads();
  for (int st = 128; st > 0; st >>= 1) {
    if (t < st) red[t] += red[t + st];
    __syncthreads();
  }
  if (t == 0) wnorm[f] = 0.5f * red[0];
}

// ---------------------------------------------------------------------------
// Kernel 2: fused x-prep + implicit-im2col GEMM, ZERO-BARRIER K-loop.
//  - xfoot (r10-verbatim): 4 padded rows x 32 x 128c bf16 in LDS,
//    swizzle byte ^= ((pix&15)<<4); all 9x im2col reuse from LDS.
//  - A: direct from global Wfrag (fragment-major) -> one coalesced 1KB
//    wave-load per fragment, uniform offsets (rr*4+ks)*8192 + mi*1024.
//    L1-hot (waves with same wr read identical lines; 288KB L2-resident).
//  - No A-LDS, no STAGE, no barriers after the prologue: fully-unrolled
//    36 steps; compiler software-pipelines global/ds loads across steps.
//  - Epilogue (r10-verbatim): Cst transpose (stride 65, aliases xfoot) ->
//    coalesced nontemporal stores, fused -wnorm[f] - 0.5||X||^2.
// ---------------------------------------------------------------------------
__global__ __launch_bounds__(256, 2) void adder_fused_kernel(
    const float* __restrict__ x,
    const unsigned short* __restrict__ Wfrag,
    const float* __restrict__ wnorm,
    float* __restrict__ out) {
  __shared__ unsigned short xfoot[128 * 130];   // 33280 B (also epilogue Cst)
  __shared__ float pixsum_s[128];
  __shared__ float xn_s[64];
  __shared__ float wn_s[F_OUT];

  int tid = threadIdx.x, lane = tid & 63, wid = tid >> 6;
  int bid0 = blockIdx.x;
  int bid = (bid0 & 7) * (NBLK / 8) + (bid0 >> 3);   // XCD-chunked, bijective
  int n = bid / TPI, timg = bid - n * TPI;
  int i0 = timg * 2, p0 = timg * BLT;

  char* XF = (char*)xfoot;

  // ---- prologue: wn load, build xfoot ----
  if (tid < F_OUT) wn_s[tid] = wnorm[tid];

  // x conversion, coalesced mapping: u = cq*28 + r*7 + w4.
  for (int u = tid; u < 896; u += 256) {
    int cq = u / 28, rem = u - cq * 28;
    int r = rem / 7, w4 = rem - r * 7;
    int c = cq * 4;
    int hr = i0 - 2 + r;
    float vv[4][4];
    if (hr >= 0 && hr < H_IN) {
#pragma unroll
      for (int q = 0; q < 4; q++) {
        float4 t4 = *(const float4*)(x + (((n * C_IN + c + q) * H_IN + hr) * H_IN + w4 * 4));
        vv[q][0] = t4.x; vv[q][1] = t4.y; vv[q][2] = t4.z; vv[q][3] = t4.w;
      }
    } else {
#pragma unroll
      for (int q = 0; q < 4; q++)
#pragma unroll
        for (int e = 0; e < 4; e++) vv[q][e] = 0.f;
    }
#pragma unroll
    for (int e = 0; e < 4; e++) {
      int wp = w4 * 4 + e + 2;            // 2..29
      int pix = r * 32 + wp;
      u16x4 o;
#pragma unroll
      for (int q = 0; q < 4; q++) o[q] = f2bf(vv[q][e]);
      *(u16x4*)(XF + pix * 256 + ((c * 2) ^ ((pix & 15) << 4))) = o;
    }
  }
  // border zeros: wp in {0,1,30,31} for all 4 rows
  {
    int r = tid >> 6, wi = (tid >> 4) & 3, slot = tid & 15;
    int wp = (wi < 2) ? wi : 28 + wi;     // 0,1,30,31
    int pix = r * 32 + wp;
    u16x8 z;
#pragma unroll
    for (int q = 0; q < 8; q++) z[q] = 0;
    *(u16x8*)(XF + pix * 256 + ((slot * 16) ^ ((pix & 15) << 4))) = z;
  }
  __syncthreads();

  // per-pixel squared channel sums (2 threads per pixel)
  {
    int pix = tid >> 1, ch = tid & 1;
    float ssum = 0.f;
#pragma unroll
    for (int q = 0; q < 8; q++) {
      u16x8 v8 = *(const u16x8*)(XF + pix * 256 + (((ch * 128) + q * 16) ^ ((pix & 15) << 4)));
#pragma unroll
      for (int e = 0; e < 8; e++) {
        union { unsigned u; float f; } cv; cv.u = ((unsigned)v8[e]) << 16;
        ssum += cv.f * cv.f;
      }
    }
    ssum += __shfl_xor(ssum, 1);
    if (!ch) pixsum_s[pix] = ssum;
  }
  __syncthreads();
  if (tid < BLT) {
    int il = tid / HO, j = tid - il * HO;
    float a9 = 0.f;
#pragma unroll
    for (int dh = 0; dh < 3; dh++)
#pragma unroll
      for (int dw = 0; dw < 3; dw++)
        a9 += pixsum_s[(il + dh) * 32 + (j + dw)];
    xn_s[tid] = 0.5f * a9;
  }
  __syncthreads();   // xfoot/xn_s visible; LAST barrier before epilogue

  // ---- K-loop: zero barriers ----
  f32x4 acc[4][2];
#pragma unroll
  for (int mi = 0; mi < 4; mi++)
#pragma unroll
    for (int ni = 0; ni < 2; ni++)
      acc[mi][ni] = (f32x4){0.f, 0.f, 0.f, 0.f};

  int wr = wid >> 1, wc = wid & 1;
  int colc = lane & 15, kg = lane >> 4;
  int kfrag = kg * 16;
  int pix0[2];
#pragma unroll
  for (int ni = 0; ni < 2; ni++) {
    int cc = wc * 32 + ni * 16 + colc;
    if (cc > BLT - 1) cc = BLT - 1;       // dead cols: valid reads, dropped later
    int il = cc / HO, j = cc - il * HO;
    pix0[ni] = il * 32 + j;
  }
  const char* Abase = (const char*)Wfrag + wr * 4096 + (size_t)lane * 16;

#pragma unroll
  for (int rr = 0; rr < 9; rr++) {
    const int dh = rr / 3, dw = rr - 3 * dh;
    const int pofs = dh * 32 + dw;
#pragma unroll
    for (int ks = 0; ks < 4; ks++) {
      bf16x8 af[4], bfv[2];
#pragma unroll
      for (int mi = 0; mi < 4; mi++)
        af[mi] = *(const bf16x8*)(Abase + ((rr * 4 + ks) * 8192 + mi * 1024));
#pragma unroll
      for (int ni = 0; ni < 2; ni++) {
        int pix = pix0[ni] + pofs;
        bfv[ni] = *(const bf16x8*)(XF + pix * 256 + ((ks * 64 + kfrag) ^ ((pix & 15) << 4)));
      }
      __builtin_amdgcn_s_setprio(1);
#pragma unroll
      for (int mi = 0; mi < 4; mi++)
#pragma unroll
        for (int ni = 0; ni < 2; ni++)
          acc[mi][ni] = __builtin_amdgcn_mfma_f32_16x16x32_bf16(
              af[mi], bfv[ni], acc[mi][ni], 0, 0, 0);
      __builtin_amdgcn_s_setprio(0);
    }
  }
  __syncthreads();   // all xfoot B-reads done before Cst alias writes

  // ---- epilogue: acc -> Cst (stride 65, aliases xfoot) -> coalesced stores ----
  float* Cst = (float*)xfoot;             // [128][65] f32 = 33280 B exactly
#pragma unroll
  for (int mi = 0; mi < 4; mi++) {
    int f0 = wr * 64 + mi * 16 + kg * 4;
#pragma unroll
    for (int ni = 0; ni < 2; ni++) {
      int cc = wc * 32 + ni * 16 + colc;
#pragma unroll
      for (int r = 0; r < 4; r++)
        Cst[(f0 + r) * 65 + cc] = acc[mi][ni][r];
    }
  }
  __syncthreads();
  {
    int col = tid & 63, fq = tid >> 6;
    if (col < BLT) {
      float xn = xn_s[col];
      float* ob = out + (size_t)n * (F_OUT * P_SP) + p0 + col;
#pragma unroll
      for (int q = 0; q < 32; q++) {
        int f = fq * 32 + q;
        __builtin_nontemporal_store(Cst[f * 65 + col] - wn_s[f] - xn, ob + f * P_SP);
      }
    }
  }
}

// ---------------------------------------------------------------------------
extern "C" void kernel_launch(void* const* d_in, const int* in_sizes, int n_in,
                              void* d_out, int out_size, void* d_ws, size_t ws_size,
                              hipStream_t stream) {
  const float* x = (const float*)d_in[0];
  const float* W = (const float*)d_in[1];
  float* out = (float*)d_out;

  char* ws = (char*)d_ws;
  unsigned short* Wfrag = (unsigned short*)(ws);     // 294,912 B
  float* wnorm = (float*)(ws + 294912);              //     512 B

  prep_w_kernel<<<F_OUT, 256, 0, stream>>>(W, Wfrag, wnorm);
  adder_fused_kernel<<<NBLK, 256, 0, stream>>>(x, Wfrag, wnorm, out);
}

// Round 13
// 27.424 us; speedup vs baseline: 4.2821x; 1.0239x over previous
//
#include <hip/hip_runtime.h>
#include <hip/hip_bf16.h>
#include <stdint.h>

// out[n,f,i,j] = sum_k W[f,k]*patch[n,i,j,k] - 0.5||W_f||^2 - 0.5||X_{n,i,j}||^2
// x: (32,128,28,28) f32 ; W: (128,128,3,3) f32 ; out: (32,128,30,30) f32
// pad=2, ho=wo=30, L=28800, K=1152, F=128

#define N_IMG 32
#define C_IN 128
#define H_IN 28
#define HP 32
#define HO 30
#define P_SP 900
#define F_OUT 128
#define K_TOT 1152

#define BLT 60              // L-tile: 2 raster rows, no image crossing
#define TPI 15              // tiles per image
#define NBLK (N_IMG*TPI)    // 480 blocks; ~67 KB LDS -> 2 blocks/CU

typedef __attribute__((ext_vector_type(8))) short bf16x8;
typedef __attribute__((ext_vector_type(4))) unsigned short u16x4;
typedef __attribute__((ext_vector_type(8))) unsigned short u16x8;
typedef __attribute__((ext_vector_type(4))) float f32x4;

__device__ __forceinline__ unsigned short f2bf(float f) {
  union { float f; unsigned u; } t; t.f = f;
  unsigned r = t.u + 0x7fffu + ((t.u >> 16) & 1u);
  return (unsigned short)(r >> 16);
}

// ---------------------------------------------------------------------------
// Kernel 1 (tiny, r10-verbatim): W -> bf16 k' = rr*128 + ch, + wnorm.
// ---------------------------------------------------------------------------
__global__ void prep_w_kernel(const float* __restrict__ W,
                              unsigned short* __restrict__ Wbf,
                              float* __restrict__ wnorm) {
  int f = blockIdx.x;
  const float* Wf = W + f * K_TOT;
  float part = 0.f;
  for (int k = threadIdx.x; k < K_TOT; k += 256) {
    float v = Wf[k];                 // k = ch*9 + rr
    part += v * v;
    int ch = k / 9, rr = k - ch * 9;
    Wbf[f * K_TOT + rr * 128 + ch] = f2bf(v);
  }
  __shared__ float red[256];
  red[threadIdx.x] = part;
  __syncthreads();
  for (int st = 128; st > 0; st >>= 1) {
    if (threadIdx.x < st) red[threadIdx.x] += red[threadIdx.x + st];
    __syncthreads();
  }
  if (threadIdx.x == 0) wnorm[f] = 0.5f * red[0];
}

// ---------------------------------------------------------------------------
// Kernel 2: fused x-prep + implicit-im2col GEMM, T14 async-split A staging.
//  - xfoot (r10-verbatim): 4 padded rows x 32 x 128c bf16, swizzled.
//  - A: SINGLE 32 KB LDS buffer (128 rows x 256 B, BK=128 = one full rr
//    slice). Per step t (9 steps): issue 8x16B coalesced reg-loads of
//    A(t+1) -> compute 64 MFMA/wave from A_lds -> syncthreads (read-done)
//    -> ds_write regs (global latency hidden under the 64-MFMA phase)
//    -> syncthreads. 18 barriers total, 64 MFMA between barriers (r10: 36/16).
//  - Swizzle convention everywhere: phys slot p of row holds logical
//    kb = (p*16) ^ ((row&7)<<4)  (involution).
//  - Epilogue (r10-verbatim): Cst transpose (stride 65, aliases xfoot) ->
//    coalesced nontemporal stores, fused -wnorm[f] - 0.5||X||^2.
// ---------------------------------------------------------------------------
__global__ __launch_bounds__(256, 2) void adder_fused_kernel(
    const float* __restrict__ x,
    const unsigned short* __restrict__ Wbf,
    const float* __restrict__ wnorm,
    float* __restrict__ out) {
  __shared__ unsigned short xfoot[128 * 130];   // 33280 B (also epilogue Cst)
  __shared__ unsigned short A_lds[128 * 128];   // 32 KB: 128 rows x 256 B
  __shared__ float pixsum_s[128];
  __shared__ float xn_s[64];
  __shared__ float wn_s[F_OUT];

  int tid = threadIdx.x, lane = tid & 63, wid = tid >> 6;
  int bid0 = blockIdx.x;
  int bid = (bid0 & 7) * (NBLK / 8) + (bid0 >> 3);   // XCD-chunked, bijective
  int n = bid / TPI, timg = bid - n * TPI;
  int i0 = timg * 2, p0 = timg * BLT;

  char* XF = (char*)xfoot;
  char* AB = (char*)A_lds;
  const char* WbfB = (const char*)Wbf;

  // ---- prologue A(0) staging via global_load_lds: 32 chunks of 1KB ----
  // chunk q: rows q*4..q*4+3 (256B each); lane l -> row q*4 + (l>>4),
  // phys slot l&15, source logical kb = ((l&15)*16) ^ ((row&7)<<4).
  {
#pragma unroll
    for (int a = 0; a < 8; a++) {
      int q = a * 4 + wid;
      int row = q * 4 + (lane >> 4);
      int goff = row * (K_TOT * 2) + (((lane & 15) * 16) ^ ((row & 7) << 4));
      __builtin_amdgcn_global_load_lds(
          (const __attribute__((address_space(1))) void*)(WbfB + goff),
          (__attribute__((address_space(3))) void*)(AB + q * 1024 + lane * 16), 16, 0, 0);
    }
  }
  if (tid < F_OUT) wn_s[tid] = wnorm[tid];

  // ---- reg-stage addresses: s in 0..7 -> row = s*16 + (tid>>4), p = tid&15
  int grs[8];
#pragma unroll
  for (int s = 0; s < 8; s++) {
    int row = s * 16 + (tid >> 4);
    grs[s] = row * (K_TOT * 2) + (((tid & 15) * 16) ^ ((row & 7) << 4));
  }

  // ---- build xfoot (r10-verbatim) ----
  for (int u = tid; u < 896; u += 256) {
    int cq = u / 28, rem = u - cq * 28;
    int r = rem / 7, w4 = rem - r * 7;
    int c = cq * 4;
    int hr = i0 - 2 + r;
    float vv[4][4];
    if (hr >= 0 && hr < H_IN) {
#pragma unroll
      for (int q = 0; q < 4; q++) {
        float4 t4 = *(const float4*)(x + (((n * C_IN + c + q) * H_IN + hr) * H_IN + w4 * 4));
        vv[q][0] = t4.x; vv[q][1] = t4.y; vv[q][2] = t4.z; vv[q][3] = t4.w;
      }
    } else {
#pragma unroll
      for (int q = 0; q < 4; q++)
#pragma unroll
        for (int e = 0; e < 4; e++) vv[q][e] = 0.f;
    }
#pragma unroll
    for (int e = 0; e < 4; e++) {
      int wp = w4 * 4 + e + 2;            // 2..29
      int pix = r * 32 + wp;
      u16x4 o;
#pragma unroll
      for (int q = 0; q < 4; q++) o[q] = f2bf(vv[q][e]);
      *(u16x4*)(XF + pix * 256 + ((c * 2) ^ ((pix & 15) << 4))) = o;
    }
  }
  {
    int r = tid >> 6, wi = (tid >> 4) & 3, slot = tid & 15;
    int wp = (wi < 2) ? wi : 28 + wi;     // 0,1,30,31
    int pix = r * 32 + wp;
    u16x8 z;
#pragma unroll
    for (int q = 0; q < 8; q++) z[q] = 0;
    *(u16x8*)(XF + pix * 256 + ((slot * 16) ^ ((pix & 15) << 4))) = z;
  }
  __syncthreads();

  // per-pixel squared channel sums (2 threads per pixel)
  {
    int pix = tid >> 1, ch = tid & 1;
    float ssum = 0.f;
#pragma unroll
    for (int q = 0; q < 8; q++) {
      u16x8 v8 = *(const u16x8*)(XF + pix * 256 + (((ch * 128) + q * 16) ^ ((pix & 15) << 4)));
#pragma unroll
      for (int e = 0; e < 8; e++) {
        union { unsigned u; float f; } cv; cv.u = ((unsigned)v8[e]) << 16;
        ssum += cv.f * cv.f;
      }
    }
    ssum += __shfl_xor(ssum, 1);
    if (!ch) pixsum_s[pix] = ssum;
  }
  __syncthreads();
  if (tid < BLT) {
    int il = tid / HO, j = tid - il * HO;
    float a9 = 0.f;
#pragma unroll
    for (int dh = 0; dh < 3; dh++)
#pragma unroll
      for (int dw = 0; dw < 3; dw++)
        a9 += pixsum_s[(il + dh) * 32 + (j + dw)];
    xn_s[tid] = 0.5f * a9;
  }
  __syncthreads();   // drains A(0) DMA; xfoot/xn_s visible

  // ---- K-loop: 9 steps of BK=128, T14 split staging ----
  f32x4 acc[4][2];
#pragma unroll
  for (int mi = 0; mi < 4; mi++)
#pragma unroll
    for (int ni = 0; ni < 2; ni++)
      acc[mi][ni] = (f32x4){0.f, 0.f, 0.f, 0.f};

  int wr = wid >> 1, wc = wid & 1;
  int colc = lane & 15, kg = lane >> 4;
  int kfrag = kg * 16;
  int pix0[2];
#pragma unroll
  for (int ni = 0; ni < 2; ni++) {
    int cc = wc * 32 + ni * 16 + colc;
    if (cc > BLT - 1) cc = BLT - 1;       // dead cols: valid reads, dropped later
    int il = cc / HO, j = cc - il * HO;
    pix0[ni] = il * 32 + j;
  }
  int arow[4], asw[4];
#pragma unroll
  for (int mi = 0; mi < 4; mi++) {
    arow[mi] = (wr * 64 + mi * 16 + colc) * 256;
    asw[mi] = ((wr * 64 + mi * 16 + colc) & 7) << 4;
  }

  u16x8 rs[8];
  for (int t = 0; t < 9; t++) {
    // issue-early: reg-load A(t+1) (coalesced, 4 rows x 256B per wave per s)
    if (t + 1 < 9) {
      int off = (t + 1) * 256;
#pragma unroll
      for (int s = 0; s < 8; s++)
        rs[s] = *(const u16x8*)(WbfB + grs[s] + off);
    }
    // compute(t): full 128-channel slice of window position t
    int dh = t / 3, dw = t - 3 * dh;
    int pofs = dh * 32 + dw;
#pragma unroll
    for (int kc = 0; kc < 4; kc++) {
      bf16x8 af[4], bfv[2];
#pragma unroll
      for (int mi = 0; mi < 4; mi++)
        af[mi] = *(const bf16x8*)(AB + arow[mi] + ((kc * 64 + kfrag) ^ asw[mi]));
#pragma unroll
      for (int ni = 0; ni < 2; ni++) {
        int pix = pix0[ni] + pofs;
        bfv[ni] = *(const bf16x8*)(XF + pix * 256 + ((kc * 64 + kfrag) ^ ((pix & 15) << 4)));
      }
      __builtin_amdgcn_s_setprio(1);
#pragma unroll
      for (int mi = 0; mi < 4; mi++)
#pragma unroll
        for (int ni = 0; ni < 2; ni++)
          acc[mi][ni] = __builtin_amdgcn_mfma_f32_16x16x32_bf16(
              af[mi], bfv[ni], acc[mi][ni], 0, 0, 0);
      __builtin_amdgcn_s_setprio(0);
    }
    __syncthreads();                      // read-done: A_lds free to overwrite
    if (t + 1 < 9) {
      // write-late: regs -> A_lds (vm latency was hidden under 64 MFMA)
#pragma unroll
      for (int s = 0; s < 8; s++)
        *(u16x8*)(AB + s * 4096 + tid * 16) = rs[s];
      __syncthreads();                    // A(t+1) visible to all waves
    }
  }

  // ---- epilogue: acc -> Cst (stride 65, aliases xfoot) -> coalesced stores ----
  float* Cst = (float*)xfoot;             // [128][65] f32 = 33280 B exactly
#pragma unroll
  for (int mi = 0; mi < 4; mi++) {
    int f0 = wr * 64 + mi * 16 + kg * 4;
#pragma unroll
    for (int ni = 0; ni < 2; ni++) {
      int cc = wc * 32 + ni * 16 + colc;
#pragma unroll
      for (int r = 0; r < 4; r++)
        Cst[(f0 + r) * 65 + cc] = acc[mi][ni][r];
    }
  }
  __syncthreads();
  {
    int col = tid & 63, fq = tid >> 6;
    if (col < BLT) {
      float xn = xn_s[col];
      float* ob = out + (size_t)n * (F_OUT * P_SP) + p0 + col;
#pragma unroll
      for (int q = 0; q < 32; q++) {
        int f = fq * 32 + q;
        __builtin_nontemporal_store(Cst[f * 65 + col] - wn_s[f] - xn, ob + f * P_SP);
      }
    }
  }
}

// ---------------------------------------------------------------------------
extern "C" void kernel_launch(void* const* d_in, const int* in_sizes, int n_in,
                              void* d_out, int out_size, void* d_ws, size_t ws_size,
                              hipStream_t stream) {
  const float* x = (const float*)d_in[0];
  const float* W = (const float*)d_in[1];
  float* out = (float*)d_out;

  char* ws = (char*)d_ws;
  unsigned short* Wbf = (unsigned short*)(ws);       // 294,912 B
  float* wnorm = (float*)(ws + 294912);              //     512 B

  prep_w_kernel<<<F_OUT, 256, 0, stream>>>(W, Wbf, wnorm);
  adder_fused_kernel<<<NBLK, 256, 0, stream>>>(x, Wbf, wnorm, out);
}